// Round 1
// baseline (372.032 us; speedup 1.0000x reference)
//
#include <hip/hip_runtime.h>

// ---------------------------------------------------------------------------
// Qwen3-style attention block on MI355X (gfx950), bf16 MFMA pipeline.
// B=2, S=1024, HID=4096, H=32, KV=8, D=128.
// Stages: cvt(f32->bf16) -> QKV GEMM -> RMSNorm+RoPE -> flash attn -> out GEMM
// ---------------------------------------------------------------------------

typedef __attribute__((ext_vector_type(8))) short s8v;            // 8 bf16 bit-patterns (4 VGPR)
typedef __attribute__((ext_vector_type(4))) float f4v;
typedef __attribute__((ext_vector_type(8))) unsigned short u8v;
typedef __attribute__((ext_vector_type(4))) float float4v;

__device__ __forceinline__ unsigned short f2b(float f) {
  unsigned u = __builtin_bit_cast(unsigned, f);
  u += 0x7fffu + ((u >> 16) & 1u);            // round-to-nearest-even
  return (unsigned short)(u >> 16);
}
__device__ __forceinline__ float b2f(unsigned short h) {
  return __builtin_bit_cast(float, (unsigned)h << 16);
}

__device__ __forceinline__ void gload16(const void* g, void* l) {
  __builtin_amdgcn_global_load_lds(
      (const __attribute__((address_space(1))) unsigned int*)g,
      (__attribute__((address_space(3))) unsigned int*)l, 16, 0, 0);
}

// ---------------------------------------------------------------------------
// f32 -> bf16 (vectorized 8/thread; all sizes are multiples of 2048)
// ---------------------------------------------------------------------------
__global__ __launch_bounds__(256) void cvt_bf16_k(const float* __restrict__ s,
                                                  unsigned short* __restrict__ d,
                                                  long n) {
  long i = ((long)blockIdx.x * 256 + threadIdx.x) * 8;
  if (i >= n) return;
  float4v a = *(const float4v*)(s + i);
  float4v b = *(const float4v*)(s + i + 4);
  u8v o;
  o[0] = f2b(a[0]); o[1] = f2b(a[1]); o[2] = f2b(a[2]); o[3] = f2b(a[3]);
  o[4] = f2b(b[0]); o[5] = f2b(b[1]); o[6] = f2b(b[2]); o[7] = f2b(b[3]);
  *(u8v*)(d + i) = o;
}

// ---------------------------------------------------------------------------
// bf16 GEMM:  C[M,N] = A[M,K] * W[N,K]^T   (both K-contiguous row-major)
// 128x128 tile, BK=32, 4 waves (2x2 of 64x64), double-buffered LDS,
// T3 minimal 2-phase prefetch, XOR-swizzled LDS via pre-swizzled source.
// ---------------------------------------------------------------------------
template <bool F32OUT>
__global__ __launch_bounds__(256) void gemm_bt(const unsigned short* __restrict__ A,
                                               const unsigned short* __restrict__ W,
                                               void* __restrict__ Cv,
                                               int M, int N, int K, int ldc) {
  __shared__ unsigned short Ab[2][128 * 32];
  __shared__ unsigned short Bb[2][128 * 32];
  const int tid = threadIdx.x;
  const int lane = tid & 63;
  const int w = tid >> 6;
  const int wr = w >> 1, wc = w & 1;
  const int lr = lane & 15, lg = lane >> 4;
  const int m0 = blockIdx.y * 128, n0 = blockIdx.x * 128;

  f4v acc[4][4];
#pragma unroll
  for (int i = 0; i < 4; ++i)
#pragma unroll
    for (int j = 0; j < 4; ++j) acc[i][j] = (f4v){0.f, 0.f, 0.f, 0.f};

  auto stage = [&](int buf, int kt) {
    const long kb = (long)kt * 32;
#pragma unroll
    for (int t = 0; t < 2; ++t) {
      int c = t * 256 + tid;
      int row = c >> 2;
      int sc = (c & 3) ^ (row & 3);                 // inverse-swizzled source chunk
      gload16(A + (long)(m0 + row) * K + kb + sc * 8, &Ab[buf][c * 8]);
    }
#pragma unroll
    for (int t = 0; t < 2; ++t) {
      int c = t * 256 + tid;
      int row = c >> 2;
      int sc = (c & 3) ^ (row & 3);
      gload16(W + (long)(n0 + row) * K + kb + sc * 8, &Bb[buf][c * 8]);
    }
  };

  const int nk = K >> 5;
  stage(0, 0);
  __syncthreads();
  int cur = 0;
  for (int kt = 0; kt < nk; ++kt) {
    if (kt + 1 < nk) stage(cur ^ 1, kt + 1);        // prefetch overlaps MFMA below
    s8v af[4], bfr[4];
#pragma unroll
    for (int i = 0; i < 4; ++i) {
      int ra = wr * 64 + i * 16 + lr;
      af[i] = *(const s8v*)&Ab[cur][ra * 32 + ((lg ^ (ra & 3)) << 3)];
      int rb = wc * 64 + i * 16 + lr;
      bfr[i] = *(const s8v*)&Bb[cur][rb * 32 + ((lg ^ (rb & 3)) << 3)];
    }
#pragma unroll
    for (int i = 0; i < 4; ++i)
#pragma unroll
      for (int j = 0; j < 4; ++j)
        acc[i][j] = __builtin_amdgcn_mfma_f32_16x16x32_bf16(af[i], bfr[j], acc[i][j], 0, 0, 0);
    __syncthreads();                                 // drains vmcnt: next tile ready
    cur ^= 1;
  }

  if constexpr (F32OUT) {
    float* C = (float*)Cv;
#pragma unroll
    for (int i = 0; i < 4; ++i) {
      int row = m0 + wr * 64 + i * 16 + lg * 4;
#pragma unroll
      for (int j = 0; j < 4; ++j) {
        int col = n0 + wc * 64 + j * 16 + lr;
#pragma unroll
        for (int r = 0; r < 4; ++r) C[(long)(row + r) * ldc + col] = acc[i][j][r];
      }
    }
  } else {
    unsigned short* C = (unsigned short*)Cv;
#pragma unroll
    for (int i = 0; i < 4; ++i) {
      int row = m0 + wr * 64 + i * 16 + lg * 4;
#pragma unroll
      for (int j = 0; j < 4; ++j) {
        int col = n0 + wc * 64 + j * 16 + lr;
#pragma unroll
        for (int r = 0; r < 4; ++r) C[(long)(row + r) * ldc + col] = f2b(acc[i][j][r]);
      }
    }
  }
}

// ---------------------------------------------------------------------------
// Per-head RMSNorm (D=128) + RoPE, in-place on the bf16 qkv buffer.
// One wave per (row, head); lane handles d=lane and d=lane+64.
// qkv row layout: [Q: 32*128][K: 8*128][V: 8*128] = 6144 cols.
// ---------------------------------------------------------------------------
__global__ __launch_bounds__(256) void rms_rope_k(unsigned short* __restrict__ qkv,
                                                  const float* __restrict__ fc,
                                                  const float* __restrict__ qw,
                                                  const float* __restrict__ kw) {
  int idx = blockIdx.x * 4 + (threadIdx.x >> 6);
  int lane = threadIdx.x & 63;
  int head = idx % 40;                 // 0..31 = Q heads, 32..39 = K heads
  int row = idx / 40;                  // b*1024 + s
  int s = row & 1023;
  unsigned short* p;
  const float* w;
  if (head < 32) { p = qkv + (long)row * 6144 + head * 128; w = qw; }
  else           { p = qkv + (long)row * 6144 + 4096 + (head - 32) * 128; w = kw; }
  float x0 = b2f(p[lane]), x1 = b2f(p[lane + 64]);
  float ss = x0 * x0 + x1 * x1;
#pragma unroll
  for (int off = 32; off; off >>= 1) ss += __shfl_xor(ss, off);
  float r = rsqrtf(ss * (1.0f / 128.0f) + 1e-6f);
  float y0 = x0 * r * w[lane], y1 = x1 * r * w[lane + 64];
  const float* cosp = fc + (long)s * 128;
  const float* sinp = cosp + 1024 * 128;
  const float* nsinp = sinp + 1024 * 128;
  float e0 = y0 * cosp[lane] + y1 * nsinp[lane];
  float e1 = y1 * cosp[lane + 64] + y0 * sinp[lane + 64];
  p[lane] = f2b(e0);
  p[lane + 64] = f2b(e1);
}

// ---------------------------------------------------------------------------
// Flash attention (no mask), GQA 4:1. Block = 4 waves = 64 q-rows; 64-key tiles.
// K staged via swizzled global_load_lds; V reg-staged transposed into [d][key]
// padded LDS; P roundtrips through per-wave swizzled LDS; online softmax (exp2).
// ---------------------------------------------------------------------------
__global__ __launch_bounds__(256) void attn_k(const unsigned short* __restrict__ qkv,
                                              unsigned short* __restrict__ ao) {
  __shared__ unsigned short Kt[64 * 128];   // [key][d], rows 256B, XOR-swizzled
  __shared__ unsigned short Vt[128 * 72];   // [d][key], padded rows (144B)
  __shared__ unsigned short Pl[4 * 1024];   // per-wave 16x64 P, XOR-swizzled

  const int bid = blockIdx.x;
  const int qt = bid & 15;
  const int h = (bid >> 4) & 31;
  const int b = bid >> 9;
  const int kvh = h >> 2;
  const int tid = threadIdx.x, lane = tid & 63, w = tid >> 6;
  const int lr = lane & 15, lg = lane >> 4;

  // Q fragments (A operand): wave's 16 q-rows, full D=128 in 4 k-steps.
  const unsigned short* Qb =
      qkv + (long)(b * 1024 + qt * 64 + w * 16 + lr) * 6144 + h * 128;
  s8v qf[4];
#pragma unroll
  for (int ks = 0; ks < 4; ++ks) qf[ks] = *(const s8v*)(Qb + ks * 32 + lg * 8);

  f4v o[8];
#pragma unroll
  for (int n = 0; n < 8; ++n) o[n] = (f4v){0.f, 0.f, 0.f, 0.f};
  float m[4], l[4];
#pragma unroll
  for (int r = 0; r < 4; ++r) { m[r] = -1e30f; l[r] = 0.f; }

  const float SL = 0.08838834764831845f * 1.4426950408889634f;  // D^-1/2 * log2(e)
  const long krow = (long)b * 1024 * 6144 + 4096 + kvh * 128;
  const long vrow = (long)b * 1024 * 6144 + 5120 + kvh * 128;

  for (int kt = 0; kt < 16; ++kt) {
    __syncthreads();   // prev iter's Kt/Vt reads complete before overwrite
    // ---- stage K tile (swizzled source -> linear LDS) ----
#pragma unroll
    for (int t = 0; t < 4; ++t) {
      int c = t * 256 + tid;
      int row = c >> 4;
      int sc = (c & 15) ^ (row & 7);
      gload16(qkv + krow + (long)(kt * 64 + row) * 6144 + sc * 8, &Kt[c * 8]);
    }
    // ---- stage V transposed (reg roundtrip; conflict-free sequential writes) ----
#pragma unroll
    for (int t = 0; t < 4; ++t) {
      int c = t * 256 + tid;
      int key = c & 63;
      int d0 = (c >> 6) * 8;
      s8v v = *(const s8v*)(qkv + vrow + (long)(kt * 64 + key) * 6144 + d0);
#pragma unroll
      for (int i = 0; i < 8; ++i) Vt[(d0 + i) * 72 + key] = (unsigned short)v[i];
    }
    __syncthreads();

    // ---- S = Q K^T (raw dot; scale folded into softmax) ----
    f4v sacc[4];
#pragma unroll
    for (int j = 0; j < 4; ++j) sacc[j] = (f4v){0.f, 0.f, 0.f, 0.f};
#pragma unroll
    for (int ks = 0; ks < 4; ++ks) {
#pragma unroll
      for (int j = 0; j < 4; ++j) {
        int key = j * 16 + lr;
        s8v kf = *(const s8v*)&Kt[key * 128 + (((ks * 64 + lg * 16) ^ ((key & 7) << 4)) >> 1)];
        sacc[j] = __builtin_amdgcn_mfma_f32_16x16x32_bf16(qf[ks], kf, sacc[j], 0, 0, 0);
      }
    }

    // ---- online softmax (exp2 domain) ----
    float sm[4];
#pragma unroll
    for (int r = 0; r < 4; ++r)
      sm[r] = fmaxf(fmaxf(sacc[0][r], sacc[1][r]), fmaxf(sacc[2][r], sacc[3][r]));
#pragma unroll
    for (int off = 1; off < 16; off <<= 1)
#pragma unroll
      for (int r = 0; r < 4; ++r) sm[r] = fmaxf(sm[r], __shfl_xor(sm[r], off));
    float alpha[4];
#pragma unroll
    for (int r = 0; r < 4; ++r) {
      float nm = fmaxf(m[r], sm[r] * SL);
      alpha[r] = exp2f(m[r] - nm);
      m[r] = nm;
      l[r] *= alpha[r];
    }
#pragma unroll
    for (int n = 0; n < 8; ++n)
#pragma unroll
      for (int r = 0; r < 4; ++r) o[n][r] *= alpha[r];

    unsigned short* pw = Pl + w * 1024;
#pragma unroll
    for (int j = 0; j < 4; ++j)
#pragma unroll
      for (int r = 0; r < 4; ++r) {
        float p = exp2f(sacc[j][r] * SL - m[r]);
        l[r] += p;
        int prow = lg * 4 + r, pcol = j * 16 + lr;
        pw[(prow * 128 + ((pcol * 2) ^ ((prow & 7) << 4))) >> 1] = f2b(p);
      }

    // ---- O += P V ---- (per-wave P region: wave-internal lgkm ordering suffices)
#pragma unroll
    for (int ks = 0; ks < 2; ++ks) {
      int bo = ks * 64 + lg * 16;
      s8v pf = *(const s8v*)&Pl[w * 1024 + ((lr * 128 + (bo ^ ((lr & 7) << 4))) >> 1)];
#pragma unroll
      for (int n = 0; n < 8; ++n) {
        s8v vf = *(const s8v*)&Vt[(n * 16 + lr) * 72 + ks * 32 + lg * 8];
        o[n] = __builtin_amdgcn_mfma_f32_16x16x32_bf16(pf, vf, o[n], 0, 0, 0);
      }
    }
  }

  // ---- finalize: reduce l across the 16-lane group, write O ----
#pragma unroll
  for (int off = 1; off < 16; off <<= 1)
#pragma unroll
    for (int r = 0; r < 4; ++r) l[r] += __shfl_xor(l[r], off);
  float inv[4];
#pragma unroll
  for (int r = 0; r < 4; ++r) inv[r] = 1.f / l[r];
  const long ob = (long)(b * 1024 + qt * 64 + w * 16) * 4096 + h * 128;
#pragma unroll
  for (int n = 0; n < 8; ++n)
#pragma unroll
    for (int r = 0; r < 4; ++r)
      ao[ob + (long)(lg * 4 + r) * 4096 + n * 16 + lr] = f2b(o[n][r] * inv[r]);
}

// ---------------------------------------------------------------------------
// Launch
// ---------------------------------------------------------------------------
extern "C" void kernel_launch(void* const* d_in, const int* in_sizes, int n_in,
                              void* d_out, int out_size, void* d_ws, size_t ws_size,
                              hipStream_t stream) {
  const float* hidden = (const float*)d_in[0];
  const float* fc     = (const float*)d_in[1];
  const float* Wq     = (const float*)d_in[2];
  const float* Wk     = (const float*)d_in[3];
  const float* Wv     = (const float*)d_in[4];
  const float* Wo     = (const float*)d_in[5];
  const float* qw     = (const float*)d_in[6];
  const float* kw     = (const float*)d_in[7];

  unsigned short* hb  = (unsigned short*)d_ws;                 // [2048][4096]
  unsigned short* wb  = hb + (long)2048 * 4096;                // [10240][4096] (Wq|Wk|Wv|Wo)
  unsigned short* qkv = wb + (long)10240 * 4096;               // [2048][6144]
  unsigned short* ao  = qkv + (long)2048 * 6144;               // [2048][4096]

  // converts (exact grids; all n divisible by 2048)
  cvt_bf16_k<<<4096, 256, 0, stream>>>(hidden, hb, (long)8388608);
  cvt_bf16_k<<<8192, 256, 0, stream>>>(Wq, wb, (long)16777216);
  cvt_bf16_k<<<2048, 256, 0, stream>>>(Wk, wb + (long)4096 * 4096, (long)4194304);
  cvt_bf16_k<<<2048, 256, 0, stream>>>(Wv, wb + (long)5120 * 4096, (long)4194304);
  cvt_bf16_k<<<8192, 256, 0, stream>>>(Wo, wb + (long)6144 * 4096, (long)16777216);

  // fused QKV projection: [2048,4096] x [6144,4096]^T -> bf16 [2048,6144]
  gemm_bt<false><<<dim3(48, 16), 256, 0, stream>>>(hb, wb, qkv, 2048, 6144, 4096, 6144);

  // per-head RMSNorm + RoPE in place (Q and K heads)
  rms_rope_k<<<20480, 256, 0, stream>>>(qkv, fc, qw, kw);

  // flash attention -> bf16 [2048][4096] (b,s,h,d)
  attn_k<<<1024, 256, 0, stream>>>(qkv, ao);

  // output projection -> f32 d_out
  gemm_bt<true><<<dim3(32, 16), 256, 0, stream>>>(ao, wb + (long)6144 * 4096, d_out,
                                                  2048, 4096, 4096, 4096);
}